// Round 2
// baseline (99.699 us; speedup 1.0000x reference)
//
#include <hip/hip_runtime.h>

// SmoothingModule: z_bar[b,t,:] = s[t], s[t] = q[t]*s[t-1] + p_eff[t]*z[t],
//   q = 1 - clip(P,0,1-1e-6), p_eff = max(clip(P,0,1-1e-6), 1e-6),
//   output zeroed for t >= lengths[b].
// Two-pass chunked scan. CHUNK=32 along T; one 128-thread block per (b,chunk);
// each thread owns one float4 column (D/4 = 128 for D=512).
// Chunks with t0 >= lengths[b] produce only zeros and are never consumed
// downstream -> early-exit (halves traffic for avg lengths ~ T/2).

#define CHUNK 32
#define BLOCK 128
#define MAX_NC 512  // supports T <= 16384

__global__ __launch_bounds__(BLOCK) void k_local(
    const float* __restrict__ z, const float* __restrict__ P,
    const int* __restrict__ lengths,
    float4* __restrict__ S, float* __restrict__ A,
    int B, int T, int D, int NC) {
  int blk = blockIdx.x;
  int b = blk / NC, c = blk % NC;
  int t0 = c * CHUNK;
  if (t0 >= lengths[b]) return;  // S/A of masked chunks are never read

  __shared__ float p_s[CHUNK], q_s[CHUNK];
  int tid = threadIdx.x;
  if (tid < CHUNK) {
    int tg = t0 + tid;
    float p = (tg < T) ? P[(size_t)b * T + tg] : 0.0f;
    p = fminf(fmaxf(p, 0.0f), 1.0f - 1e-6f);
    q_s[tid] = 1.0f - p;
    p_s[tid] = fmaxf(p, 1e-6f);
  }
  __syncthreads();

  int nt = min(CHUNK, T - t0);
  int D4 = D >> 2;
  const float4* zp = (const float4*)z + ((size_t)b * T + t0) * D4;
  for (int d4 = tid; d4 < D4; d4 += BLOCK) {
    float4 s = make_float4(0.f, 0.f, 0.f, 0.f);
    float r = 1.0f;
    if (nt == CHUNK) {
#pragma unroll
      for (int t = 0; t < CHUNK; ++t) {
        float4 zv = zp[(size_t)t * D4 + d4];
        float q = q_s[t], pe = p_s[t];
        s.x = fmaf(q, s.x, pe * zv.x);
        s.y = fmaf(q, s.y, pe * zv.y);
        s.z = fmaf(q, s.z, pe * zv.z);
        s.w = fmaf(q, s.w, pe * zv.w);
        r *= q;
      }
    } else {
      for (int t = 0; t < nt; ++t) {
        float4 zv = zp[(size_t)t * D4 + d4];
        float q = q_s[t], pe = p_s[t];
        s.x = fmaf(q, s.x, pe * zv.x);
        s.y = fmaf(q, s.y, pe * zv.y);
        s.z = fmaf(q, s.z, pe * zv.z);
        s.w = fmaf(q, s.w, pe * zv.w);
        r *= q;
      }
    }
    S[((size_t)b * NC + c) * D4 + d4] = s;
    if (d4 == 0) A[b * NC + c] = r;
  }
}

__global__ __launch_bounds__(BLOCK) void k_apply(
    const float* __restrict__ z, const float* __restrict__ P,
    const float4* __restrict__ S, const float* __restrict__ A,
    const int* __restrict__ lengths, float* __restrict__ out,
    int B, int T, int D, int NC) {
  int blk = blockIdx.x;
  int b = blk / NC, c = blk % NC;
  int t0 = c * CHUNK;
  int tid = threadIdx.x;
  int L = lengths[b];
  int nt = min(CHUNK, T - t0);
  int D4 = D >> 2;
  float4* op = (float4*)out + ((size_t)b * T + t0) * D4;

  if (t0 >= L) {  // fully masked chunk: just zero the output
    float4 zero = make_float4(0.f, 0.f, 0.f, 0.f);
    for (int d4 = tid; d4 < D4; d4 += BLOCK)
      for (int t = 0; t < nt; ++t) op[(size_t)t * D4 + d4] = zero;
    return;
  }

  __shared__ float p_s[CHUNK], q_s[CHUNK];
  __shared__ float a_s[MAX_NC];
  if (tid < CHUNK) {
    int tg = t0 + tid;
    float p = (tg < T) ? P[(size_t)b * T + tg] : 0.0f;
    p = fminf(fmaxf(p, 0.0f), 1.0f - 1e-6f);
    q_s[tid] = 1.0f - p;
    p_s[tid] = fmaxf(p, 1e-6f);
  }
  for (int i = tid; i < c; i += BLOCK) a_s[i] = A[b * NC + i];
  __syncthreads();

  const float4* Sb = S + (size_t)b * NC * D4;
  const float4* zp = (const float4*)z + ((size_t)b * T + t0) * D4;
  for (int d4 = tid; d4 < D4; d4 += BLOCK) {
    // carry-in: sum over prior chunks, weight = product of later chunk decays
    float4 s = make_float4(0.f, 0.f, 0.f, 0.f);
    float w = 1.0f;
    for (int cp = c - 1; cp >= 0; --cp) {
      float4 sv = Sb[(size_t)cp * D4 + d4];
      s.x = fmaf(sv.x, w, s.x);
      s.y = fmaf(sv.y, w, s.y);
      s.z = fmaf(sv.z, w, s.z);
      s.w = fmaf(sv.w, w, s.w);
      w *= a_s[cp];
    }
    if (nt == CHUNK && t0 + CHUNK <= L) {  // fast path: full chunk, no mask
#pragma unroll
      for (int t = 0; t < CHUNK; ++t) {
        float4 zv = zp[(size_t)t * D4 + d4];
        float q = q_s[t], pe = p_s[t];
        s.x = fmaf(q, s.x, pe * zv.x);
        s.y = fmaf(q, s.y, pe * zv.y);
        s.z = fmaf(q, s.z, pe * zv.z);
        s.w = fmaf(q, s.w, pe * zv.w);
        op[(size_t)t * D4 + d4] = s;
      }
    } else {
      float4 zero = make_float4(0.f, 0.f, 0.f, 0.f);
      for (int t = 0; t < nt; ++t) {
        float4 zv = zp[(size_t)t * D4 + d4];
        float q = q_s[t], pe = p_s[t];
        s.x = fmaf(q, s.x, pe * zv.x);
        s.y = fmaf(q, s.y, pe * zv.y);
        s.z = fmaf(q, s.z, pe * zv.z);
        s.w = fmaf(q, s.w, pe * zv.w);
        op[(size_t)t * D4 + d4] = ((t0 + t) < L) ? s : zero;
      }
    }
  }
}

extern "C" void kernel_launch(void* const* d_in, const int* in_sizes, int n_in,
                              void* d_out, int out_size, void* d_ws, size_t ws_size,
                              hipStream_t stream) {
  const float* z = (const float*)d_in[0];
  const float* P = (const float*)d_in[1];
  const int* lengths = (const int*)d_in[2];
  float* out = (float*)d_out;

  int B = in_sizes[2];
  int T = in_sizes[1] / B;
  int D = in_sizes[0] / in_sizes[1];
  int NC = (T + CHUNK - 1) / CHUNK;

  // workspace: S [B*NC*D] floats (as float4), then A [B*NC] floats
  float4* S = (float4*)d_ws;
  float* A = (float*)d_ws + (size_t)B * NC * D;

  dim3 grid(B * NC), block(BLOCK);
  k_local<<<grid, block, 0, stream>>>(z, P, lengths, S, A, B, T, D, NC);
  k_apply<<<grid, block, 0, stream>>>(z, P, S, A, lengths, out, B, T, D, NC);
}